// Round 13
// baseline (41.036 us; speedup 1.0000x reference)
//
#include <hip/hip_runtime.h>

#define NTIMES 8
#define NFREQS 64
#define NSRC   512
#define NBL    66
#define KHALF  33
#define C_MPS  299792458.0f

// DPP-based wave64 reduction (VALU-only, no LDS). Full sum lands in lane 63.
template <int CTRL, int ROW_MASK>
__device__ __forceinline__ float dpp_add(float v) {
    const int moved = __builtin_amdgcn_update_dpp(
        0, __builtin_bit_cast(int, v), CTRL, ROW_MASK, 0xf, true);
    return v + __builtin_bit_cast(float, moved);
}
__device__ __forceinline__ float wave_sum_lane63(float v) {
    v = dpp_add<0x111, 0xf>(v); // row_shr:1
    v = dpp_add<0x112, 0xf>(v); // row_shr:2
    v = dpp_add<0x114, 0xf>(v); // row_shr:4
    v = dpp_add<0x118, 0xf>(v); // row_shr:8  -> lane15 of each row = row sum
    v = dpp_add<0x142, 0xa>(v); // row_bcast:15 into rows 1,3
    v = dpp_add<0x143, 0xc>(v); // row_bcast:31 into rows 2,3 -> lane63 = total
    return v;
}

// INSTRUMENTED PROBE ROUND: r9 kernel with phase 2 repeated Rrep times.
// asm-volatile opacity on (coefrev, weight offset, accumulator seed) prevents
// LICM from hoisting the trig / LDS-load / reduction chains out of the r-loop.
// Output identical each pass -> deterministic, same absmax as r9.
__global__ __launch_bounds__(512) void rime_kernel(
    const float* __restrict__ sky,       // [2][2][64][512]
    const float* __restrict__ beam,      // [2][2][8][64][512]
    const float* __restrict__ antpos,    // [12][3]
    const float* __restrict__ svec,      // [8][3][512]
    const float* __restrict__ freqs,     // [64]
    const int*   __restrict__ ant2model, // [12]
    const int*   __restrict__ bls,       // [66][2]
    float*       __restrict__ out,
    int Rrep)
{
    __shared__ float  wsm[16 * NSRC]; // [c][pq][s], 32 KB
    __shared__ float4 btab[NBL];      // (blvec.xyz, bitcast class)

    const int bid = blockIdx.x;
    const int f  = bid & (NFREQS - 1);
    const int t  = (bid >> 6) & (NTIMES - 1);
    const int kh = bid >> 9; // 0 or 1

    const int tid  = threadIdx.x; // 0..511
    const int lane = tid & 63;
    const int wv   = tid >> 6;    // 0..7

    // ---- Phase 1a: baseline metadata table (threads 0..65) ----
    if (tid < NBL) {
        const int a1 = bls[2 * tid + 0];
        const int a2 = bls[2 * tid + 1];
        float4 e;
        e.x = antpos[3 * a2 + 0] - antpos[3 * a1 + 0];
        e.y = antpos[3 * a2 + 1] - antpos[3 * a1 + 1];
        e.z = antpos[3 * a2 + 2] - antpos[3 * a1 + 2];
        e.w = __builtin_bit_cast(float, ant2model[a1] * 2 + ant2model[a2]);
        btab[tid] = e;
    }

    // ---- Phase 1b: thread == source; build 16 weight vectors in LDS ----
    {
        const int s = tid;
        const size_t beam_tf = (size_t)t * NFREQS * NSRC + (size_t)f * NSRC + s;
        float bv[2][2]; // [p][m]
        bv[0][0] = beam[(size_t)0 * NTIMES * NFREQS * NSRC + beam_tf];
        bv[0][1] = beam[(size_t)1 * NTIMES * NFREQS * NSRC + beam_tf];
        bv[1][0] = beam[(size_t)2 * NTIMES * NFREQS * NSRC + beam_tf];
        bv[1][1] = beam[(size_t)3 * NTIMES * NFREQS * NSRC + beam_tf];
        const size_t sky_f = (size_t)f * NSRC + s;
        float skv[4];
        skv[0] = sky[(size_t)0 * NFREQS * NSRC + sky_f];
        skv[1] = sky[(size_t)1 * NFREQS * NSRC + sky_f];
        skv[2] = sky[(size_t)2 * NFREQS * NSRC + sky_f];
        skv[3] = sky[(size_t)3 * NFREQS * NSRC + sky_f];
#pragma unroll
        for (int m1 = 0; m1 < 2; ++m1)
#pragma unroll
            for (int m2 = 0; m2 < 2; ++m2)
#pragma unroll
                for (int pq = 0; pq < 4; ++pq) {
                    const int p = pq >> 1, q = pq & 1;
                    wsm[((m1 * 2 + m2) * 4 + pq) * NSRC + s] =
                        bv[p][m1] * skv[pq] * bv[q][m2];
                }
    }

    // per-lane svec registers (baseline-invariant)
    const float4* sv4 = (const float4*)(svec + (size_t)t * 3 * NSRC);
    float4 vx[2], vy[2], vz[2];
#pragma unroll
    for (int it = 0; it < 2; ++it) {
        vx[it] = sv4[lane + 64 * it];
        vy[it] = sv4[128 + lane + 64 * it];
        vz[it] = sv4[256 + lane + 64 * it];
    }

    // phase in REVOLUTIONS for v_cos: rev = (-f/c) * (blvec . svec)
    const float coefrev = -freqs[f] / C_MPS;

    __syncthreads();

    for (int r = 0; r < Rrep; ++r) {
        // opacity: compiler must treat these as fresh each pass
        float    coefrev_r = coefrev;
        float    zero      = 0.f;
        unsigned wofs      = 0;
        asm volatile("" : "+v"(coefrev_r), "+v"(zero), "+v"(wofs));

        // ---- Phase 2: wave wv handles kk = wv + 8*i, i = 0..4 (unrolled) ----
#pragma unroll
        for (int i = 0; i < 5; ++i) {
            const int kk = wv + 8 * i;
            if (kk < KHALF) {
                const int k = kh * KHALF + kk;
                const float4 m = btab[k];
                const int   c   = __builtin_bit_cast(int, m.w);
                const float bxc = coefrev_r * m.x;
                const float byc = coefrev_r * m.y;
                const float bzc = coefrev_r * m.z;
                const float4* wp =
                    (const float4*)(wsm + (size_t)c * 4 * NSRC + wofs);

                float a00 = zero, a01 = zero, a10 = zero, a11 = zero;
#pragma unroll
                for (int it = 0; it < 2; ++it) {
                    const int s4 = lane + 64 * it;
                    const float4 w00 = wp[s4];          // pq stride = 128 f4
                    const float4 w01 = wp[128 + s4];
                    const float4 w10 = wp[256 + s4];
                    const float4 w11 = wp[384 + s4];

#define RIME_BODY(CX)                                                          \
                    {                                                          \
                        const float rev = __builtin_amdgcn_fractf(             \
                            bxc * vx[it].CX + byc * vy[it].CX + bzc * vz[it].CX); \
                        const float cs = __builtin_amdgcn_cosf(rev);           \
                        a00 += w00.CX * cs;                                    \
                        a01 += w01.CX * cs;                                    \
                        a10 += w10.CX * cs;                                    \
                        a11 += w11.CX * cs;                                    \
                    }
                    RIME_BODY(x)
                    RIME_BODY(y)
                    RIME_BODY(z)
                    RIME_BODY(w)
#undef RIME_BODY
                }

                const float s00 = wave_sum_lane63(a00);
                const float s01 = wave_sum_lane63(a01);
                const float s10 = wave_sum_lane63(a10);
                const float s11 = wave_sum_lane63(a11);

                if (lane == 63) {
                    const int base = k * (NTIMES * NFREQS) + t * NFREQS + f;
                    const int pqs  = NBL * NTIMES * NFREQS; // 33792
                    out[base]           = s00;
                    out[base + pqs]     = s01;
                    out[base + 2 * pqs] = s10;
                    out[base + 3 * pqs] = s11;
                }
            }
        }
    }
}

extern "C" void kernel_launch(void* const* d_in, const int* in_sizes, int n_in,
                              void* d_out, int out_size, void* d_ws, size_t ws_size,
                              hipStream_t stream) {
    const float* sky     = (const float*)d_in[0];
    const float* beam    = (const float*)d_in[1];
    const float* antpos  = (const float*)d_in[2];
    const float* svec    = (const float*)d_in[3];
    const float* freqs   = (const float*)d_in[4];
    const int*   ant2mod = (const int*)d_in[5];
    const int*   bls     = (const int*)d_in[6];
    float*       out     = (float*)d_out;

    const int nblocks = NTIMES * NFREQS * 2; // 1024: (t, f, khalf)
    rime_kernel<<<nblocks, 512, 0, stream>>>(sky, beam, antpos, svec, freqs,
                                             ant2mod, bls, out, /*Rrep=*/5);
}

// Round 14
// 14.783 us; speedup vs baseline: 2.7758x; 2.7758x over previous
//
#include <hip/hip_runtime.h>

#define NTIMES 8
#define NFREQS 64
#define NSRC   512
#define NBL    66
#define KHALF  33
#define C_MPS  299792458.0f

typedef float v2f __attribute__((ext_vector_type(2)));

#if defined(__has_builtin)
#if __has_builtin(__builtin_elementwise_fma)
#define FMA2(a, b, c) __builtin_elementwise_fma((a), (b), (c))
#endif
#endif
#ifndef FMA2
static __device__ __forceinline__ v2f fma2_fallback(v2f a, v2f b, v2f c) {
    v2f r; r.x = fmaf(a.x, b.x, c.x); r.y = fmaf(a.y, b.y, c.y); return r;
}
#define FMA2(a, b, c) fma2_fallback((a), (b), (c))
#endif

// DPP-based wave64 reduction (VALU-only, no LDS). Full sum lands in lane 63.
template <int CTRL, int ROW_MASK>
__device__ __forceinline__ float dpp_add(float v) {
    const int moved = __builtin_amdgcn_update_dpp(
        0, __builtin_bit_cast(int, v), CTRL, ROW_MASK, 0xf, true);
    return v + __builtin_bit_cast(float, moved);
}
__device__ __forceinline__ float wave_sum_lane63(float v) {
    v = dpp_add<0x111, 0xf>(v); // row_shr:1
    v = dpp_add<0x112, 0xf>(v); // row_shr:2
    v = dpp_add<0x114, 0xf>(v); // row_shr:4
    v = dpp_add<0x118, 0xf>(v); // row_shr:8  -> lane15 of each row = row sum
    v = dpp_add<0x142, 0xa>(v); // row_bcast:15 into rows 1,3
    v = dpp_add<0x143, 0xc>(v); // row_bcast:31 into rows 2,3 -> lane63 = total
    return v;
}

// Output: Re(vis): [2][2][66][8][64] float32 (135168 elems).
// Block = (t, f, khalf). r9 structure; inner math in packed-f32 (v_pk_fma_f32).
__global__ __launch_bounds__(512) void rime_kernel(
    const float* __restrict__ sky,       // [2][2][64][512]
    const float* __restrict__ beam,      // [2][2][8][64][512]
    const float* __restrict__ antpos,    // [12][3]
    const float* __restrict__ svec,      // [8][3][512]
    const float* __restrict__ freqs,     // [64]
    const int*   __restrict__ ant2model, // [12]
    const int*   __restrict__ bls,       // [66][2]
    float*       __restrict__ out)
{
    __shared__ float  wsm[16 * NSRC]; // [c][pq][s], 32 KB
    __shared__ float4 btab[NBL];      // (blvec.xyz, bitcast class)

    const int bid = blockIdx.x;
    const int f  = bid & (NFREQS - 1);
    const int t  = (bid >> 6) & (NTIMES - 1);
    const int kh = bid >> 9; // 0 or 1

    const int tid  = threadIdx.x; // 0..511
    const int lane = tid & 63;
    const int wv   = tid >> 6;    // 0..7

    // ---- Phase 1a: baseline metadata table (threads 0..65) ----
    if (tid < NBL) {
        const int a1 = bls[2 * tid + 0];
        const int a2 = bls[2 * tid + 1];
        float4 e;
        e.x = antpos[3 * a2 + 0] - antpos[3 * a1 + 0];
        e.y = antpos[3 * a2 + 1] - antpos[3 * a1 + 1];
        e.z = antpos[3 * a2 + 2] - antpos[3 * a1 + 2];
        e.w = __builtin_bit_cast(float, ant2model[a1] * 2 + ant2model[a2]);
        btab[tid] = e;
    }

    // ---- Phase 1b: thread == source; build 16 weight vectors in LDS ----
    {
        const int s = tid;
        const size_t beam_tf = (size_t)t * NFREQS * NSRC + (size_t)f * NSRC + s;
        float bv[2][2]; // [p][m]
        bv[0][0] = beam[(size_t)0 * NTIMES * NFREQS * NSRC + beam_tf];
        bv[0][1] = beam[(size_t)1 * NTIMES * NFREQS * NSRC + beam_tf];
        bv[1][0] = beam[(size_t)2 * NTIMES * NFREQS * NSRC + beam_tf];
        bv[1][1] = beam[(size_t)3 * NTIMES * NFREQS * NSRC + beam_tf];
        const size_t sky_f = (size_t)f * NSRC + s;
        float skv[4];
        skv[0] = sky[(size_t)0 * NFREQS * NSRC + sky_f];
        skv[1] = sky[(size_t)1 * NFREQS * NSRC + sky_f];
        skv[2] = sky[(size_t)2 * NFREQS * NSRC + sky_f];
        skv[3] = sky[(size_t)3 * NFREQS * NSRC + sky_f];
        // factored: h[pq][m2] = skv[pq]*bv[q][m2] (8 mul), w = bv[p][m1]*h (16)
        float h[4][2];
#pragma unroll
        for (int pq = 0; pq < 4; ++pq) {
            const int q = pq & 1;
            h[pq][0] = skv[pq] * bv[q][0];
            h[pq][1] = skv[pq] * bv[q][1];
        }
#pragma unroll
        for (int m1 = 0; m1 < 2; ++m1)
#pragma unroll
            for (int m2 = 0; m2 < 2; ++m2)
#pragma unroll
                for (int pq = 0; pq < 4; ++pq) {
                    const int p = pq >> 1;
                    wsm[((m1 * 2 + m2) * 4 + pq) * NSRC + s] =
                        bv[p][m1] * h[pq][m2];
                }
    }

    // per-lane svec registers (baseline-invariant)
    const float4* sv4 = (const float4*)(svec + (size_t)t * 3 * NSRC);
    float4 vx[2], vy[2], vz[2];
#pragma unroll
    for (int it = 0; it < 2; ++it) {
        vx[it] = sv4[lane + 64 * it];
        vy[it] = sv4[128 + lane + 64 * it];
        vz[it] = sv4[256 + lane + 64 * it];
    }

    // phase in REVOLUTIONS for v_cos: rev = (-f/c) * (blvec . svec)
    const float coefrev = -freqs[f] / C_MPS;

    __syncthreads();

    // ---- Phase 2: wave wv handles kk = wv + 8*i, i = 0..4 (unrolled) ----
#pragma unroll
    for (int i = 0; i < 5; ++i) {
        const int kk = wv + 8 * i;
        if (kk < KHALF) {
            const int k = kh * KHALF + kk;
            const float4 m = btab[k];
            const int   c   = __builtin_bit_cast(int, m.w);
            const float bxc = coefrev * m.x;
            const float byc = coefrev * m.y;
            const float bzc = coefrev * m.z;
            const v2f bx2 = { bxc, bxc };
            const v2f by2 = { byc, byc };
            const v2f bz2 = { bzc, bzc };
            const float4* wp = (const float4*)(wsm + (size_t)c * 4 * NSRC);

            v2f a00v = {0.f, 0.f}, a01v = {0.f, 0.f};
            v2f a10v = {0.f, 0.f}, a11v = {0.f, 0.f};
#pragma unroll
            for (int it = 0; it < 2; ++it) {
                const int s4 = lane + 64 * it;
                const float4 w00 = wp[s4];          // pq stride = 128 float4
                const float4 w01 = wp[128 + s4];
                const float4 w10 = wp[256 + s4];
                const float4 w11 = wp[384 + s4];

                // view float4s as two v2f halves (free subregister views)
                const v2f* vxp = (const v2f*)&vx[it];
                const v2f* vyp = (const v2f*)&vy[it];
                const v2f* vzp = (const v2f*)&vz[it];
                const v2f* w00p = (const v2f*)&w00;
                const v2f* w01p = (const v2f*)&w01;
                const v2f* w10p = (const v2f*)&w10;
                const v2f* w11p = (const v2f*)&w11;

#pragma unroll
                for (int h = 0; h < 2; ++h) {
                    // packed dot: rev2 = bx2*vx + by2*vy + bz2*vz
                    v2f rev2 = FMA2(bx2, vxp[h],
                               FMA2(by2, vyp[h], bz2 * vzp[h]));
                    const float r0 = __builtin_amdgcn_fractf(rev2.x);
                    const float r1 = __builtin_amdgcn_fractf(rev2.y);
                    v2f cs2;
                    cs2.x = __builtin_amdgcn_cosf(r0);
                    cs2.y = __builtin_amdgcn_cosf(r1);
                    a00v = FMA2(w00p[h], cs2, a00v);
                    a01v = FMA2(w01p[h], cs2, a01v);
                    a10v = FMA2(w10p[h], cs2, a10v);
                    a11v = FMA2(w11p[h], cs2, a11v);
                }
            }

            // collapse pairs, then VALU (DPP) reduction to lane 63
            const float s00 = wave_sum_lane63(a00v.x + a00v.y);
            const float s01 = wave_sum_lane63(a01v.x + a01v.y);
            const float s10 = wave_sum_lane63(a10v.x + a10v.y);
            const float s11 = wave_sum_lane63(a11v.x + a11v.y);

            if (lane == 63) {
                const int base = k * (NTIMES * NFREQS) + t * NFREQS + f;
                const int pqs  = NBL * NTIMES * NFREQS; // 33792
                out[base]           = s00;
                out[base + pqs]     = s01;
                out[base + 2 * pqs] = s10;
                out[base + 3 * pqs] = s11;
            }
        }
    }
}

extern "C" void kernel_launch(void* const* d_in, const int* in_sizes, int n_in,
                              void* d_out, int out_size, void* d_ws, size_t ws_size,
                              hipStream_t stream) {
    const float* sky     = (const float*)d_in[0];
    const float* beam    = (const float*)d_in[1];
    const float* antpos  = (const float*)d_in[2];
    const float* svec    = (const float*)d_in[3];
    const float* freqs   = (const float*)d_in[4];
    const int*   ant2mod = (const int*)d_in[5];
    const int*   bls     = (const int*)d_in[6];
    float*       out     = (float*)d_out;

    const int nblocks = NTIMES * NFREQS * 2; // 1024: (t, f, khalf)
    rime_kernel<<<nblocks, 512, 0, stream>>>(sky, beam, antpos, svec, freqs,
                                             ant2mod, bls, out);
}

// Round 15
// 14.470 us; speedup vs baseline: 2.8358x; 1.0216x over previous
//
#include <hip/hip_runtime.h>

#define NTIMES 8
#define NFREQS 64
#define NSRC   512
#define NBL    66
#define C_MPS  299792458.0f

typedef float v2f __attribute__((ext_vector_type(2)));

#if defined(__has_builtin)
#if __has_builtin(__builtin_elementwise_fma)
#define FMA2(a, b, c) __builtin_elementwise_fma((a), (b), (c))
#endif
#endif
#ifndef FMA2
static __device__ __forceinline__ v2f fma2_fallback(v2f a, v2f b, v2f c) {
    v2f r; r.x = fmaf(a.x, b.x, c.x); r.y = fmaf(a.y, b.y, c.y); return r;
}
#define FMA2(a, b, c) fma2_fallback((a), (b), (c))
#endif

// DPP-based wave64 reduction (VALU-only, no LDS). Full sum lands in lane 63.
template <int CTRL, int ROW_MASK>
__device__ __forceinline__ float dpp_add(float v) {
    const int moved = __builtin_amdgcn_update_dpp(
        0, __builtin_bit_cast(int, v), CTRL, ROW_MASK, 0xf, true);
    return v + __builtin_bit_cast(float, moved);
}
__device__ __forceinline__ float wave_sum_lane63(float v) {
    v = dpp_add<0x111, 0xf>(v); // row_shr:1
    v = dpp_add<0x112, 0xf>(v); // row_shr:2
    v = dpp_add<0x114, 0xf>(v); // row_shr:4
    v = dpp_add<0x118, 0xf>(v); // row_shr:8  -> lane15 of each row = row sum
    v = dpp_add<0x142, 0xa>(v); // row_bcast:15 into rows 1,3
    v = dpp_add<0x143, 0xc>(v); // row_bcast:31 into rows 2,3 -> lane63 = total
    return v;
}

// Output: Re(vis): [2][2][66][8][64] float32 (135168 elems).
// Block = (t, f), 1024 threads (16 waves). Phase 1 builds the 16 weight
// vectors ONCE per (t,f) (each thread does its m1-half for its source).
// Phase 2: 16 waves sweep 66 baselines; packed-f32 math; no v_fract
// (|rev| <= ~71 revolutions, within v_cos HW range +-256).
__global__ __launch_bounds__(1024) void rime_kernel(
    const float* __restrict__ sky,       // [2][2][64][512]
    const float* __restrict__ beam,      // [2][2][8][64][512]
    const float* __restrict__ antpos,    // [12][3]
    const float* __restrict__ svec,      // [8][3][512]
    const float* __restrict__ freqs,     // [64]
    const int*   __restrict__ ant2model, // [12]
    const int*   __restrict__ bls,       // [66][2]
    float*       __restrict__ out)
{
    __shared__ float  wsm[16 * NSRC]; // [c=(m1*2+m2)][pq][s], 32 KB
    __shared__ float4 btab[NBL];      // (blvec.xyz, bitcast class)

    const int bid = blockIdx.x;
    const int f = bid & (NFREQS - 1);
    const int t = bid >> 6;

    const int tid  = threadIdx.x; // 0..1023
    const int lane = tid & 63;
    const int wv   = tid >> 6;    // 0..15

    // ---- Phase 1a: baseline metadata table (threads 0..65) ----
    if (tid < NBL) {
        const int a1 = bls[2 * tid + 0];
        const int a2 = bls[2 * tid + 1];
        float4 e;
        e.x = antpos[3 * a2 + 0] - antpos[3 * a1 + 0];
        e.y = antpos[3 * a2 + 1] - antpos[3 * a1 + 1];
        e.z = antpos[3 * a2 + 2] - antpos[3 * a1 + 2];
        e.w = __builtin_bit_cast(float, ant2model[a1] * 2 + ant2model[a2]);
        btab[tid] = e;
    }

    // ---- Phase 1b: (source, m1-half) per thread; 8 weight entries each ----
    {
        const int s  = tid & (NSRC - 1);
        const int m1 = tid >> 9; // 0 or 1
        const size_t beam_tf = (size_t)t * NFREQS * NSRC + (size_t)f * NSRC + s;
        float bv[2][2]; // [p][m]
        bv[0][0] = beam[(size_t)0 * NTIMES * NFREQS * NSRC + beam_tf];
        bv[0][1] = beam[(size_t)1 * NTIMES * NFREQS * NSRC + beam_tf];
        bv[1][0] = beam[(size_t)2 * NTIMES * NFREQS * NSRC + beam_tf];
        bv[1][1] = beam[(size_t)3 * NTIMES * NFREQS * NSRC + beam_tf];
        const size_t sky_f = (size_t)f * NSRC + s;
        float skv[4];
        skv[0] = sky[(size_t)0 * NFREQS * NSRC + sky_f];
        skv[1] = sky[(size_t)1 * NFREQS * NSRC + sky_f];
        skv[2] = sky[(size_t)2 * NFREQS * NSRC + sky_f];
        skv[3] = sky[(size_t)3 * NFREQS * NSRC + sky_f];
#pragma unroll
        for (int m2 = 0; m2 < 2; ++m2)
#pragma unroll
            for (int pq = 0; pq < 4; ++pq) {
                const int p = pq >> 1, q = pq & 1;
                wsm[((m1 * 2 + m2) * 4 + pq) * NSRC + s] =
                    bv[p][m1] * skv[pq] * bv[q][m2];
            }
    }

    // per-lane svec registers (baseline-invariant; same for every wave)
    const float4* sv4 = (const float4*)(svec + (size_t)t * 3 * NSRC);
    float4 vx[2], vy[2], vz[2];
#pragma unroll
    for (int it = 0; it < 2; ++it) {
        vx[it] = sv4[lane + 64 * it];
        vy[it] = sv4[128 + lane + 64 * it];
        vz[it] = sv4[256 + lane + 64 * it];
    }

    // phase in REVOLUTIONS for v_cos: rev = (-f/c) * (blvec . svec)
    const float coefrev = -freqs[f] / C_MPS;

    __syncthreads();

    // ---- Phase 2: wave wv handles k = wv + 16*i (i=0..3 always; i=4 if wv<2)
#pragma unroll
    for (int i = 0; i < 5; ++i) {
        const int k = wv + 16 * i;
        if (i < 4 || k < NBL) {
            const float4 m = btab[k];
            const int   c   = __builtin_bit_cast(int, m.w);
            const float bxc = coefrev * m.x;
            const float byc = coefrev * m.y;
            const float bzc = coefrev * m.z;
            const v2f bx2 = { bxc, bxc };
            const v2f by2 = { byc, byc };
            const v2f bz2 = { bzc, bzc };
            const float4* wp = (const float4*)(wsm + (size_t)c * 4 * NSRC);

            v2f a00v = {0.f, 0.f}, a01v = {0.f, 0.f};
            v2f a10v = {0.f, 0.f}, a11v = {0.f, 0.f};
#pragma unroll
            for (int it = 0; it < 2; ++it) {
                const int s4 = lane + 64 * it;
                const float4 w00 = wp[s4];          // pq stride = 128 float4
                const float4 w01 = wp[128 + s4];
                const float4 w10 = wp[256 + s4];
                const float4 w11 = wp[384 + s4];

                const v2f* vxp = (const v2f*)&vx[it];
                const v2f* vyp = (const v2f*)&vy[it];
                const v2f* vzp = (const v2f*)&vz[it];
                const v2f* w00p = (const v2f*)&w00;
                const v2f* w01p = (const v2f*)&w01;
                const v2f* w10p = (const v2f*)&w10;
                const v2f* w11p = (const v2f*)&w11;

#pragma unroll
                for (int h = 0; h < 2; ++h) {
                    // packed dot: rev2 = bx2*vx + by2*vy + bz2*vz  (revolutions)
                    v2f rev2 = FMA2(bx2, vxp[h],
                               FMA2(by2, vyp[h], bz2 * vzp[h]));
                    v2f cs2;
                    cs2.x = __builtin_amdgcn_cosf(rev2.x); // |rev| <= ~71 rev
                    cs2.y = __builtin_amdgcn_cosf(rev2.y); // within HW range
                    a00v = FMA2(w00p[h], cs2, a00v);
                    a01v = FMA2(w01p[h], cs2, a01v);
                    a10v = FMA2(w10p[h], cs2, a10v);
                    a11v = FMA2(w11p[h], cs2, a11v);
                }
            }

            const float s00 = wave_sum_lane63(a00v.x + a00v.y);
            const float s01 = wave_sum_lane63(a01v.x + a01v.y);
            const float s10 = wave_sum_lane63(a10v.x + a10v.y);
            const float s11 = wave_sum_lane63(a11v.x + a11v.y);

            if (lane == 63) {
                const int base = k * (NTIMES * NFREQS) + t * NFREQS + f;
                const int pqs  = NBL * NTIMES * NFREQS; // 33792
                out[base]           = s00;
                out[base + pqs]     = s01;
                out[base + 2 * pqs] = s10;
                out[base + 3 * pqs] = s11;
            }
        }
    }
}

extern "C" void kernel_launch(void* const* d_in, const int* in_sizes, int n_in,
                              void* d_out, int out_size, void* d_ws, size_t ws_size,
                              hipStream_t stream) {
    const float* sky     = (const float*)d_in[0];
    const float* beam    = (const float*)d_in[1];
    const float* antpos  = (const float*)d_in[2];
    const float* svec    = (const float*)d_in[3];
    const float* freqs   = (const float*)d_in[4];
    const int*   ant2mod = (const int*)d_in[5];
    const int*   bls     = (const int*)d_in[6];
    float*       out     = (float*)d_out;

    const int nblocks = NTIMES * NFREQS; // 512: (t, f)
    rime_kernel<<<nblocks, 1024, 0, stream>>>(sky, beam, antpos, svec, freqs,
                                              ant2mod, bls, out);
}